// Round 4
// baseline (594.968 us; speedup 1.0000x reference)
//
#include <hip/hip_runtime.h>

typedef __attribute__((ext_vector_type(4))) float f32x4;
typedef __attribute__((ext_vector_type(8))) short s16x8;

#define MFMA_16x16x32_BF16 __builtin_amdgcn_mfma_f32_16x16x32_bf16

__device__ __forceinline__ unsigned short f2bf(float f) {
  unsigned int u = __builtin_bit_cast(unsigned int, f);
  unsigned int r = (u + 0x7FFFu + ((u >> 16) & 1u)) >> 16;  // RNE
  return (unsigned short)r;
}

__device__ __forceinline__ float fexp2(float x) {
#if __has_builtin(__builtin_amdgcn_exp2f)
  return __builtin_amdgcn_exp2f(x);
#else
  float r;
  asm("v_exp_f32 %0, %1" : "=v"(r) : "v"(x));
  return r;
#endif
}

#define RCP __builtin_amdgcn_rcpf
#define L2E 1.442695040888963f   // 1/ln2
#define L2E2 2.885390081777927f  // 2/ln2

// ---- kernel 0: pack Wc = [W_ih | W_hh] (512 x 256) -> bf16, fused bias ----
__global__ __launch_bounds__(256) void pack_kernel(
    const float* __restrict__ Wih, const float* __restrict__ Whh,
    const float* __restrict__ bih, const float* __restrict__ bhh,
    unsigned short* __restrict__ Wc, float* __restrict__ biasC) {
  int i = blockIdx.x * 256 + threadIdx.x;  // 32768 chunks of 4 elems
  int col = i >> 6;
  int k4 = (i & 63) << 2;
  const float* src = (k4 < 128) ? (Wih + col * 128 + k4)
                                : (Whh + col * 128 + (k4 - 128));
  const float4 v = *reinterpret_cast<const float4*>(src);
  ushort4 u;
  u.x = f2bf(v.x); u.y = f2bf(v.y); u.z = f2bf(v.z); u.w = f2bf(v.w);
  *reinterpret_cast<ushort4*>(Wc + (size_t)col * 256 + k4) = u;
  if (i < 512) biasC[i] = bih[i] + bhh[i];
}

// ---- kernel A: attn[b,:] = softmax_d( sum_t x[b,t,:] * wt[t] ) ----
__global__ __launch_bounds__(64) void attn_kernel(
    const float* __restrict__ x, const float* __restrict__ Wattn,
    float* __restrict__ attn) {
  const int b = blockIdx.x;
  const int l = threadIdx.x;  // 0..63
  const float* xb = x + (size_t)b * 64 * 128;
  const float wtl = Wattn[256 + l];
  float s0 = 0.f, s1 = 0.f;
  for (int t = 0; t < 64; ++t) {
    float w = __shfl(wtl, t, 64);
    s0 = fmaf(xb[t * 128 + l], w, s0);
    s1 = fmaf(xb[t * 128 + 64 + l], w, s1);
  }
  float m = fmaxf(s0, s1);
  for (int off = 32; off; off >>= 1) m = fmaxf(m, __shfl_xor(m, off, 64));
  float e0 = __expf(s0 - m), e1 = __expf(s1 - m);
  float sum = e0 + e1;
  for (int off = 32; off; off >>= 1) sum += __shfl_xor(sum, off, 64);
  float inv = RCP(sum);
  attn[(size_t)b * 128 + l] = e0 * inv;
  attn[(size_t)b * 128 + 64 + l] = e1 * inv;
}

// ---- kernel B: persistent LSTM recurrence, 8 rows/block, grid 512 ----
// 2 blocks/CU for cross-block latency hiding. 512 thr = 8 waves; wave w owns
// gate cols {g*128 + w*16 + l15}; i/f/g/o lane-local. bfr = 64 VGPR loaded
// once (bf16). A-tile 16x256 (rows 8..15 zeroed once; MFMA M=16 half-wasted,
// MFMA pipe has headroom). XOR-swizzled LDS. EW on lanes 0..31 (rows 0..7),
// fused-reciprocal exp2 forms.
__global__ __launch_bounds__(512, 4) void lstm_kernel(
    const float* __restrict__ x, const unsigned short* __restrict__ Wc,
    const float* __restrict__ biasC, const float* __restrict__ attn,
    float* __restrict__ out) {
  __shared__ __attribute__((aligned(16))) unsigned short sA[16 * 256];
  char* sAb = reinterpret_cast<char*>(sA);

  const int tid = threadIdx.x;
  const int l = tid & 63;
  const int w = tid >> 6;   // wave 0..7 (also this thread's staging row)
  const int l15 = l & 15;
  const int khi = l >> 4;   // 0..3
  const int rowBase = blockIdx.x * 8;

  // ---- load B fragments (bf16) into registers (once) ----
  s16x8 bfr[4][8];
  float bias2[4];
#pragma unroll
  for (int g = 0; g < 4; ++g) {
    const int col = g * 128 + w * 16 + l15;
    const unsigned short* p = Wc + (size_t)col * 256 + khi * 8;
#pragma unroll
    for (int kt = 0; kt < 8; ++kt)
      bfr[g][kt] = *reinterpret_cast<const s16x8*>(p + kt * 32);
    const float sc = (g == 2) ? L2E2 : -L2E;
    bias2[g] = sc * biasC[col];
  }

  // ---- staging role: wave w stages row w; lane l covers cols 2l, 2l+1 ----
  const float2 at2 =
      *reinterpret_cast<const float2*>(attn + (size_t)(rowBase + w) * 128 + l * 2);
  const float* xrow = x + (size_t)(rowBase + w) * 8192 + l * 2;
  const int stg_off = w * 512 + ((l * 4) ^ (w << 4));

  // ---- zero h-half of rows 0..7 and all of rows 8..15 (once) ----
  if (tid < 128) {
    const int row = tid >> 4;
    const int byte = (256 + ((tid & 15) << 4)) ^ ((row & 7) << 4);
    int4 z = {0, 0, 0, 0};
    *reinterpret_cast<int4*>(sAb + row * 512 + byte) = z;
  } else if (tid < 384) {
    int4 z = {0, 0, 0, 0};
    *reinterpret_cast<int4*>(sAb + 4096 + (tid - 128) * 16) = z;
  }

  float c4[4] = {0.f, 0.f, 0.f, 0.f};
  float2 xv = *reinterpret_cast<const float2*>(xrow);  // x(0)

  const char* aRd = sAb + l15 * 512;
  float* outP = out + (size_t)(rowBase + khi * 4) * 8192 + w * 16 + l15;

  __syncthreads();

  for (int t = 0; t < 64; ++t) {
    // P1: stage w_in(t) = attn * x_t (bf16, ushort2 per lane)
    {
      ushort2 u;
      u.x = f2bf(xv.x * at2.x);
      u.y = f2bf(xv.y * at2.y);
      *reinterpret_cast<ushort2*>(sAb + stg_off) = u;
    }
    // prefetch next x
    xv = *reinterpret_cast<const float2*>(xrow + ((t + 1) & 63) * 128);
    __syncthreads();  // B1: A-tile complete

    // P2: gates = A @ Wc^T (K = 256)
    f32x4 acc[4];
#pragma unroll
    for (int g = 0; g < 4; ++g) acc[g] = f32x4{0.f, 0.f, 0.f, 0.f};
#pragma unroll
    for (int kt = 0; kt < 8; ++kt) {
      const s16x8 af = *reinterpret_cast<const s16x8*>(
          aRd + ((kt * 64 + khi * 16) ^ ((l15 & 7) << 4)));
#pragma unroll
      for (int g = 0; g < 4; ++g)
        acc[g] = MFMA_16x16x32_BF16(af, bfr[g][kt], acc[g], 0, 0, 0);
    }

    // P3a: elementwise LSTM cell + output store (rows 0..7 live in lanes<32)
    float hreg[4];
    if (l < 32) {
#pragma unroll
      for (int rr = 0; rr < 4; ++rr) {
        const float Ei = fexp2(fminf(fmaf(acc[0][rr], -L2E, bias2[0]), 30.f));
        const float Ef = fexp2(fminf(fmaf(acc[1][rr], -L2E, bias2[1]), 30.f));
        const float G  = fexp2(fminf(fmaf(acc[2][rr],  L2E2, bias2[2]), 30.f));
        const float Eo = fexp2(fminf(fmaf(acc[3][rr], -L2E, bias2[3]), 30.f));
        const float a1 = 1.f + Ei, a2 = 1.f + Ef, a3 = G + 1.f, a4 = G - 1.f;
        const float m1 = a1 * a3;
        const float num = fmaf(a2, a4, c4[rr] * m1);
        const float cn = num * RCP(a2 * m1);
        c4[rr] = cn;
        const float C2 = fexp2(fminf(cn * L2E2, 30.f));
        const float h = (C2 - 1.f) * RCP((1.f + Eo) * (C2 + 1.f));
        hreg[rr] = h;
        outP[(size_t)rr * 8192 + t * 128] = h;
      }
    }
    __syncthreads();  // B2: all MFMA reads of sA done

    // P3b: write h(t) bf16 into h-half (rows 0..7)
    if (l < 32) {
#pragma unroll
      for (int rr = 0; rr < 4; ++rr) {
        const int row = khi * 4 + rr;
        const int byte = (256 + ((w * 16 + l15) << 1)) ^ (row << 4);
        *reinterpret_cast<unsigned short*>(sAb + row * 512 + byte) =
            f2bf(hreg[rr]);
      }
    }
    // no barrier: next P1 writes disjoint region; B1 orders before MFMA
  }
}

extern "C" void kernel_launch(void* const* d_in, const int* in_sizes, int n_in,
                              void* d_out, int out_size, void* d_ws, size_t ws_size,
                              hipStream_t stream) {
  const float* x     = (const float*)d_in[0];  // (4096, 64, 128)
  const float* W_ih  = (const float*)d_in[1];  // (512, 128)
  const float* W_hh  = (const float*)d_in[2];  // (512, 128)
  const float* b_ih  = (const float*)d_in[3];  // (512,)
  const float* b_hh  = (const float*)d_in[4];  // (512,)
  const float* Wattn = (const float*)d_in[5];  // (1, 320)
  float* out = (float*)d_out;                  // (4096, 64, 128)

  // workspace layout
  float* attn = (float*)d_ws;                                            // 2 MB
  unsigned short* Wc = (unsigned short*)((char*)d_ws + 4096 * 128 * 4);  // 256 KB
  float* biasC = (float*)((char*)d_ws + 4096 * 128 * 4 + 512 * 256 * 2); // 2 KB

  pack_kernel<<<128, 256, 0, stream>>>(W_ih, W_hh, b_ih, b_hh, Wc, biasC);
  attn_kernel<<<4096, 64, 0, stream>>>(x, Wattn, attn);
  lstm_kernel<<<512, 512, 0, stream>>>(x, Wc, biasC, attn, out);
}

// Round 5
// 114.035 us; speedup vs baseline: 5.2174x; 5.2174x over previous
//
#include <hip/hip_runtime.h>

typedef __attribute__((ext_vector_type(4))) float f32x4;
typedef __attribute__((ext_vector_type(8))) short s16x8;

#define MFMA_16x16x32_BF16 __builtin_amdgcn_mfma_f32_16x16x32_bf16

__device__ __forceinline__ unsigned short f2bf(float f) {
  unsigned int u = __builtin_bit_cast(unsigned int, f);
  unsigned int r = (u + 0x7FFFu + ((u >> 16) & 1u)) >> 16;  // RNE
  return (unsigned short)r;
}

__device__ __forceinline__ float fexp2(float x) {
#if __has_builtin(__builtin_amdgcn_exp2f)
  return __builtin_amdgcn_exp2f(x);
#else
  float r;
  asm("v_exp_f32 %0, %1" : "=v"(r) : "v"(x));
  return r;
#endif
}

// LDS-only barrier: orders ds ops but leaves global loads/stores (vmcnt)
// in flight — __syncthreads would drain vmcnt(0), serializing the x-prefetch
// and out-store latency into every step.
__device__ __forceinline__ void lds_barrier() {
  asm volatile("s_waitcnt lgkmcnt(0)" ::: "memory");
  __builtin_amdgcn_s_barrier();
}

#define RCP __builtin_amdgcn_rcpf
#define L2E 1.442695040888963f   // 1/ln2
#define L2E2 2.885390081777927f  // 2/ln2

// ---- kernel 0: pack Wc = [W_ih | W_hh] (512 x 256) -> bf16, fused bias ----
__global__ __launch_bounds__(256) void pack_kernel(
    const float* __restrict__ Wih, const float* __restrict__ Whh,
    const float* __restrict__ bih, const float* __restrict__ bhh,
    unsigned short* __restrict__ Wc, float* __restrict__ biasC) {
  int i = blockIdx.x * 256 + threadIdx.x;  // 32768 chunks of 4 elems
  int col = i >> 6;
  int k4 = (i & 63) << 2;
  const float* src = (k4 < 128) ? (Wih + col * 128 + k4)
                                : (Whh + col * 128 + (k4 - 128));
  const float4 v = *reinterpret_cast<const float4*>(src);
  ushort4 u;
  u.x = f2bf(v.x); u.y = f2bf(v.y); u.z = f2bf(v.z); u.w = f2bf(v.w);
  *reinterpret_cast<ushort4*>(Wc + (size_t)col * 256 + k4) = u;
  if (i < 512) {
    // pre-scale: gates i,f,o use -1/ln2 (sigmoid exp2 form); g uses 2/ln2
    const float b = bih[i] + bhh[i];
    biasC[i] = ((i >> 7) == 2 ? L2E2 : -L2E) * b;
  }
}

// ---- kernel A: attn[b,:] = softmax_d( sum_t x[b,t,:] * wt[t] ) ----
__global__ __launch_bounds__(64) void attn_kernel(
    const float* __restrict__ x, const float* __restrict__ Wattn,
    float* __restrict__ attn) {
  const int b = blockIdx.x;
  const int l = threadIdx.x;  // 0..63
  const float* xb = x + (size_t)b * 64 * 128;
  const float wtl = Wattn[256 + l];
  float s0 = 0.f, s1 = 0.f;
  for (int t = 0; t < 64; ++t) {
    float w = __shfl(wtl, t, 64);
    s0 = fmaf(xb[t * 128 + l], w, s0);
    s1 = fmaf(xb[t * 128 + 64 + l], w, s1);
  }
  float m = fmaxf(s0, s1);
  for (int off = 32; off; off >>= 1) m = fmaxf(m, __shfl_xor(m, off, 64));
  float e0 = __expf(s0 - m), e1 = __expf(s1 - m);
  float sum = e0 + e1;
  for (int off = 32; off; off >>= 1) sum += __shfl_xor(sum, off, 64);
  float inv = RCP(sum);
  attn[(size_t)b * 128 + l] = e0 * inv;
  attn[(size_t)b * 128 + 64 + l] = e1 * inv;
}

// ---- kernel B: persistent LSTM recurrence, weights in registers ----
// R2 structure (known-good): 512 thr = 8 waves, 16 rows/block, grid 256,
// 1 block/CU (bfr = 128 VGPR/wave forces this — see R4 post-mortem).
// Only change: lds_barrier() instead of __syncthreads() so global ops
// stay in flight across the two per-step barriers.
__global__ __launch_bounds__(512, 2) void lstm_kernel(
    const float* __restrict__ x, const unsigned short* __restrict__ Wc,
    const float* __restrict__ biasC, const float* __restrict__ attn,
    float* __restrict__ out) {
  __shared__ __attribute__((aligned(16))) unsigned short sA[16 * 256];
  char* sAb = reinterpret_cast<char*>(sA);

  const int tid = threadIdx.x;
  const int l = tid & 63;
  const int w = tid >> 6;   // 0..7
  const int l15 = l & 15;
  const int khi = l >> 4;   // 0..3
  const int rowBase = blockIdx.x * 16;

  // ---- load B fragments into registers (once) ----
  s16x8 bfr[4][8];
  float bias2[4];
#pragma unroll
  for (int g = 0; g < 4; ++g) {
    const int col = g * 128 + w * 16 + l15;
    const unsigned short* p = Wc + (size_t)col * 256 + khi * 8;
#pragma unroll
    for (int kt = 0; kt < 8; ++kt)
      bfr[g][kt] = *reinterpret_cast<const s16x8*>(p + kt * 32);
    bias2[g] = biasC[col];
  }

  // ---- staging role: thread -> (row r_st, 4 cols at c_st) ----
  const int r_st = tid >> 5;          // 0..15
  const int c_st = (tid & 31) << 2;   // 0..124
  const float4 at =
      *reinterpret_cast<const float4*>(attn + (size_t)(rowBase + r_st) * 128 + c_st);
  const float* xrow = x + (size_t)(rowBase + r_st) * 8192 + c_st;
  char* stg_ptr = sAb + r_st * 512 + ((c_st << 1) ^ ((r_st & 7) << 4));

  // zero h-half (t=0): thread covers row r_st, 8 bytes
  {
    int hb = (256 + ((tid & 31) << 3)) ^ ((r_st & 7) << 4);
    uint2 z = {0u, 0u};
    *reinterpret_cast<uint2*>(sAb + r_st * 512 + hb) = z;
  }

  float c4[4] = {0.f, 0.f, 0.f, 0.f};
  float4 xv = *reinterpret_cast<const float4*>(xrow);  // t = 0

  const char* aRd = sAb + l15 * 512;
  float* outP = out + (size_t)(rowBase + khi * 4) * 8192 + w * 16 + l15;

  lds_barrier();

  for (int t = 0; t < 64; ++t) {
    // P1: stage w_in = attn * x_t (bf16)
    {
      ushort4 u;
      u.x = f2bf(xv.x * at.x); u.y = f2bf(xv.y * at.y);
      u.z = f2bf(xv.z * at.z); u.w = f2bf(xv.w * at.w);
      *reinterpret_cast<ushort4*>(stg_ptr) = u;
    }
    // prefetch next x tile (long-latency, consumed next iter; NOT drained
    // by the raw barriers below)
    xv = *reinterpret_cast<const float4*>(xrow + ((t + 1) & 63) * 128);
    lds_barrier();  // B1: A-tile complete

    // P2: gates = A @ Wc^T (K = 256)
    f32x4 acc[4];
#pragma unroll
    for (int g = 0; g < 4; ++g) acc[g] = f32x4{0.f, 0.f, 0.f, 0.f};
#pragma unroll
    for (int kt = 0; kt < 8; ++kt) {
      const s16x8 af = *reinterpret_cast<const s16x8*>(
          aRd + ((kt * 64 + khi * 16) ^ ((l15 & 7) << 4)));
#pragma unroll
      for (int g = 0; g < 4; ++g)
        acc[g] = MFMA_16x16x32_BF16(af, bfr[g][kt], acc[g], 0, 0, 0);
    }

    // P3a: elementwise LSTM cell + output store (fused-reciprocal exp2)
    float hreg[4];
#pragma unroll
    for (int rr = 0; rr < 4; ++rr) {
      const float Ei = fexp2(fminf(fmaf(acc[0][rr], -L2E, bias2[0]), 30.f));
      const float Ef = fexp2(fminf(fmaf(acc[1][rr], -L2E, bias2[1]), 30.f));
      const float G  = fexp2(fminf(fmaf(acc[2][rr],  L2E2, bias2[2]), 30.f));
      const float Eo = fexp2(fminf(fmaf(acc[3][rr], -L2E, bias2[3]), 30.f));
      // c' = [c*(1+Ei)(G+1) + (1+Ef)(G-1)] / [(1+Ef)(1+Ei)(G+1)]
      const float a1 = 1.f + Ei, a2 = 1.f + Ef, a3 = G + 1.f, a4 = G - 1.f;
      const float m1 = a1 * a3;
      const float num = fmaf(a2, a4, c4[rr] * m1);
      const float cn = num * RCP(a2 * m1);
      c4[rr] = cn;
      // h = (e^{2c'}-1) / [(1+Eo)(e^{2c'}+1)]
      const float C2 = fexp2(fminf(cn * L2E2, 30.f));
      const float h = (C2 - 1.f) * RCP((1.f + Eo) * (C2 + 1.f));
      hreg[rr] = h;
      outP[(size_t)rr * 8192 + t * 128] = h;  // fire-and-forget
    }
    lds_barrier();  // B2: all MFMA reads of sA done before h overwrite

    // P3b: write h (bf16) into h-half for next step
#pragma unroll
    for (int rr = 0; rr < 4; ++rr) {
      const int row = khi * 4 + rr;
      const int hb = (256 + ((w * 16 + l15) << 1)) ^ ((row & 7) << 4);
      *reinterpret_cast<unsigned short*>(sAb + row * 512 + hb) = f2bf(hreg[rr]);
    }
    // no barrier: next P1 writes disjoint region; B1 orders before MFMA
  }
}

extern "C" void kernel_launch(void* const* d_in, const int* in_sizes, int n_in,
                              void* d_out, int out_size, void* d_ws, size_t ws_size,
                              hipStream_t stream) {
  const float* x     = (const float*)d_in[0];  // (4096, 64, 128)
  const float* W_ih  = (const float*)d_in[1];  // (512, 128)
  const float* W_hh  = (const float*)d_in[2];  // (512, 128)
  const float* b_ih  = (const float*)d_in[3];  // (512,)
  const float* b_hh  = (const float*)d_in[4];  // (512,)
  const float* Wattn = (const float*)d_in[5];  // (1, 320)
  float* out = (float*)d_out;                  // (4096, 64, 128)

  // workspace layout
  float* attn = (float*)d_ws;                                            // 2 MB
  unsigned short* Wc = (unsigned short*)((char*)d_ws + 4096 * 128 * 4);  // 256 KB
  float* biasC = (float*)((char*)d_ws + 4096 * 128 * 4 + 512 * 256 * 2); // 2 KB

  pack_kernel<<<128, 256, 0, stream>>>(W_ih, W_hh, b_ih, b_hh, Wc, biasC);
  attn_kernel<<<4096, 64, 0, stream>>>(x, Wattn, attn);
  lstm_kernel<<<256, 512, 0, stream>>>(x, Wc, biasC, attn, out);
}

// Round 6
// 112.194 us; speedup vs baseline: 5.3030x; 1.0164x over previous
//
#include <hip/hip_runtime.h>

typedef __attribute__((ext_vector_type(4))) float f32x4;
typedef __attribute__((ext_vector_type(8))) short s16x8;

#define MFMA_16x16x32_BF16 __builtin_amdgcn_mfma_f32_16x16x32_bf16

__device__ __forceinline__ unsigned short f2bf(float f) {
  unsigned int u = __builtin_bit_cast(unsigned int, f);
  unsigned int r = (u + 0x7FFFu + ((u >> 16) & 1u)) >> 16;  // RNE
  return (unsigned short)r;
}

__device__ __forceinline__ unsigned int cvt_pk_bf16(float lo, float hi) {
  unsigned int r;
  asm("v_cvt_pk_bf16_f32 %0, %1, %2" : "=v"(r) : "v"(lo), "v"(hi));
  return r;
}

__device__ __forceinline__ float fexp2(float x) {
#if __has_builtin(__builtin_amdgcn_exp2f)
  return __builtin_amdgcn_exp2f(x);
#else
  float r;
  asm("v_exp_f32 %0, %1" : "=v"(r) : "v"(x));
  return r;
#endif
}

// LDS-only barrier: orders ds ops but leaves global loads/stores in flight.
__device__ __forceinline__ void lds_barrier() {
  asm volatile("s_waitcnt lgkmcnt(0)" ::: "memory");
  __builtin_amdgcn_s_barrier();
}

#define RCP __builtin_amdgcn_rcpf
#define L2E 1.442695040888963f   // 1/ln2
#define L2E2 2.885390081777927f  // 2/ln2

// ---- kernel 0: pack Wc = [W_ih | W_hh] (512 x 256) -> bf16, fused bias ----
__global__ __launch_bounds__(256) void pack_kernel(
    const float* __restrict__ Wih, const float* __restrict__ Whh,
    const float* __restrict__ bih, const float* __restrict__ bhh,
    unsigned short* __restrict__ Wc, float* __restrict__ biasC) {
  int i = blockIdx.x * 256 + threadIdx.x;  // 32768 chunks of 4 elems
  int col = i >> 6;
  int k4 = (i & 63) << 2;
  const float* src = (k4 < 128) ? (Wih + col * 128 + k4)
                                : (Whh + col * 128 + (k4 - 128));
  const float4 v = *reinterpret_cast<const float4*>(src);
  ushort4 u;
  u.x = f2bf(v.x); u.y = f2bf(v.y); u.z = f2bf(v.z); u.w = f2bf(v.w);
  *reinterpret_cast<ushort4*>(Wc + (size_t)col * 256 + k4) = u;
  if (i < 512) {
    const float b = bih[i] + bhh[i];
    biasC[i] = ((i >> 7) == 2 ? L2E2 : -L2E) * b;  // pre-scaled for exp2 form
  }
}

// ---- kernel A: attn[b,:] = softmax_d( sum_t x[b,t,:] * wt[t] ) ----
__global__ __launch_bounds__(64) void attn_kernel(
    const float* __restrict__ x, const float* __restrict__ Wattn,
    float* __restrict__ attn) {
  const int b = blockIdx.x;
  const int l = threadIdx.x;  // 0..63
  const float* xb = x + (size_t)b * 64 * 128;
  const float wtl = Wattn[256 + l];
  float s0 = 0.f, s1 = 0.f;
  for (int t = 0; t < 64; ++t) {
    float w = __shfl(wtl, t, 64);
    s0 = fmaf(xb[t * 128 + l], w, s0);
    s1 = fmaf(xb[t * 128 + 64 + l], w, s1);
  }
  float m = fmaxf(s0, s1);
  for (int off = 32; off; off >>= 1) m = fmaxf(m, __shfl_xor(m, off, 64));
  float e0 = __expf(s0 - m), e1 = __expf(s1 - m);
  float sum = e0 + e1;
  for (int off = 32; off; off >>= 1) sum += __shfl_xor(sum, off, 64);
  float inv = RCP(sum);
  attn[(size_t)b * 128 + l] = e0 * inv;
  attn[(size_t)b * 128 + 64 + l] = e1 * inv;
}

// ---- kernel B: persistent LSTM recurrence, weights in registers ----
// 512 thr = 8 waves, 16 rows/block, grid 256 (1 block/CU, structural —
// bfr = 128 VGPR/wave). ONE lds_barrier per step: w_in AND h tiles are
// double-buffered (read buf[cur], write buf[nxt]); own ds_reads drained by
// lgkmcnt(0) before the barrier, so next step's overwrites can't race.
// LDS map (byte offsets): wbuf0 @0, wbuf1 @4096, hbuf0 @8192, hbuf1 @12288.
// Each: 16 rows x 128 bf16, row stride 256 B, swizzle byte ^= (row&7)<<4.
__global__ __launch_bounds__(512, 2) void lstm_kernel(
    const float* __restrict__ x, const unsigned short* __restrict__ Wc,
    const float* __restrict__ biasC, const float* __restrict__ attn,
    float* __restrict__ out) {
  __shared__ __attribute__((aligned(16))) char sAb[16384];

  const int tid = threadIdx.x;
  const int l = tid & 63;
  const int w = tid >> 6;   // 0..7
  const int l15 = l & 15;
  const int khi = l >> 4;   // 0..3
  const int rowBase = blockIdx.x * 16;

  // ---- B fragments into registers (once): 4 gates x 8 kt x 16B ----
  s16x8 bfr[4][8];
  float bias2[4];
#pragma unroll
  for (int g = 0; g < 4; ++g) {
    const int col = g * 128 + w * 16 + l15;
    const unsigned short* p = Wc + (size_t)col * 256 + khi * 8;
#pragma unroll
    for (int kt = 0; kt < 8; ++kt)
      bfr[g][kt] = *reinterpret_cast<const s16x8*>(p + kt * 32);
    bias2[g] = biasC[col];
  }

  // ---- staging role: thread -> (row r_st, 4 cols at c_st) ----
  const int r_st = tid >> 5;          // 0..15
  const int c_st = (tid & 31) << 2;   // 0..124
  const float4 at =
      *reinterpret_cast<const float4*>(attn + (size_t)(rowBase + r_st) * 128 + c_st);
  const float* xrow = x + (size_t)(rowBase + r_st) * 8192 + c_st;
  char* stgW = sAb + r_st * 256 + ((c_st << 1) ^ ((r_st & 7) << 4));

  // zero hbuf0 (swizzle permutes within buffer; zeros unaffected)
  {
    uint2 z = {0u, 0u};
    *reinterpret_cast<uint2*>(sAb + 8192 + tid * 8) = z;
  }

  // stage w_in(0) into wbuf0; prefetch x(1)
  float4 xv = *reinterpret_cast<const float4*>(xrow);
  {
    uint2 u;
    u.x = cvt_pk_bf16(xv.x * at.x, xv.y * at.y);
    u.y = cvt_pk_bf16(xv.z * at.z, xv.w * at.w);
    *reinterpret_cast<uint2*>(stgW) = u;
  }
  xv = *reinterpret_cast<const float4*>(xrow + 128);

  // ---- MFMA read pointers (even-step layout; odd adds +4096) ----
  const char* aw[4];
  const char* ah[4];
#pragma unroll
  for (int k = 0; k < 4; ++k) {
    aw[k] = sAb + l15 * 256 + ((k * 64 + khi * 16) ^ ((l15 & 7) << 4));
    ah[k] = aw[k] + 8192;
  }

  // ---- h-write pointers: base at hbuf0; step cur=0 adds +4096 (hbuf1) ----
  char* hw[4];
#pragma unroll
  for (int rr = 0; rr < 4; ++rr) {
    const int row = khi * 4 + rr;
    hw[rr] = sAb + 8192 + row * 256 + (((w * 16 + l15) << 1) ^ ((row & 7) << 4));
  }

  float c4[4] = {0.f, 0.f, 0.f, 0.f};
  float* outP = out + (size_t)(rowBase + khi * 4) * 8192 + w * 16 + l15;

  lds_barrier();

  for (int tt = 0; tt < 32; ++tt) {
#pragma unroll
    for (int half = 0; half < 2; ++half) {
      const int t = tt * 2 + half;
      const int WNXT = half ? 0 : 4096;   // wbuf[nxt] offset from wbuf0
      const int RCUR = half ? 4096 : 0;   // read-buffer offset
      const int HNXT = half ? 0 : 4096;   // hbuf[nxt] offset from hbuf0

      // P1: stage w_in(t+1) into wbuf[nxt] (xv = x(t+1))
      {
        uint2 u;
        u.x = cvt_pk_bf16(xv.x * at.x, xv.y * at.y);
        u.y = cvt_pk_bf16(xv.z * at.z, xv.w * at.w);
        *reinterpret_cast<uint2*>(stgW + WNXT) = u;
      }
      xv = *reinterpret_cast<const float4*>(xrow + ((t + 2) & 63) * 128);

      // P2: gates = A @ Wc^T (K = 256), reads buf[cur]
      f32x4 acc[4];
#pragma unroll
      for (int g = 0; g < 4; ++g) acc[g] = f32x4{0.f, 0.f, 0.f, 0.f};
      __builtin_amdgcn_s_setprio(1);
#pragma unroll
      for (int k = 0; k < 4; ++k) {
        const s16x8 af = *reinterpret_cast<const s16x8*>(aw[k] + RCUR);
#pragma unroll
        for (int g = 0; g < 4; ++g)
          acc[g] = MFMA_16x16x32_BF16(af, bfr[g][k], acc[g], 0, 0, 0);
      }
#pragma unroll
      for (int k = 0; k < 4; ++k) {
        const s16x8 af = *reinterpret_cast<const s16x8*>(ah[k] + RCUR);
#pragma unroll
        for (int g = 0; g < 4; ++g)
          acc[g] = MFMA_16x16x32_BF16(af, bfr[g][4 + k], acc[g], 0, 0, 0);
      }
      __builtin_amdgcn_s_setprio(0);

      // P3a: elementwise LSTM cell + output store (fused-reciprocal exp2)
      float h4[4];
#pragma unroll
      for (int rr = 0; rr < 4; ++rr) {
        const float Ei = fexp2(fminf(fmaf(acc[0][rr], -L2E, bias2[0]), 30.f));
        const float Ef = fexp2(fminf(fmaf(acc[1][rr], -L2E, bias2[1]), 30.f));
        const float G  = fexp2(fminf(fmaf(acc[2][rr],  L2E2, bias2[2]), 30.f));
        const float Eo = fexp2(fminf(fmaf(acc[3][rr], -L2E, bias2[3]), 30.f));
        const float a1 = 1.f + Ei, a2 = 1.f + Ef, a3 = G + 1.f, a4 = G - 1.f;
        const float m1 = a1 * a3;
        const float num = fmaf(a2, a4, c4[rr] * m1);
        const float cn = num * RCP(a2 * m1);
        c4[rr] = cn;
        const float C2 = fexp2(fminf(cn * L2E2, 30.f));
        const float h = (C2 - 1.f) * RCP((1.f + Eo) * (C2 + 1.f));
        h4[rr] = h;
        outP[(size_t)rr * 8192 + t * 128] = h;  // fire-and-forget
      }

      // P3b: h(t) -> bf16 -> hbuf[nxt] (read next step as A rows)
      {
        const unsigned int r01 = cvt_pk_bf16(h4[0], h4[1]);
        const unsigned int r23 = cvt_pk_bf16(h4[2], h4[3]);
        *reinterpret_cast<unsigned short*>(hw[0] + HNXT) = (unsigned short)r01;
        *reinterpret_cast<unsigned short*>(hw[1] + HNXT) =
            (unsigned short)(r01 >> 16);
        *reinterpret_cast<unsigned short*>(hw[2] + HNXT) = (unsigned short)r23;
        *reinterpret_cast<unsigned short*>(hw[3] + HNXT) =
            (unsigned short)(r23 >> 16);
      }

      lds_barrier();  // single barrier: all cur-reads drained, nxt complete
    }
  }
}

extern "C" void kernel_launch(void* const* d_in, const int* in_sizes, int n_in,
                              void* d_out, int out_size, void* d_ws, size_t ws_size,
                              hipStream_t stream) {
  const float* x     = (const float*)d_in[0];  // (4096, 64, 128)
  const float* W_ih  = (const float*)d_in[1];  // (512, 128)
  const float* W_hh  = (const float*)d_in[2];  // (512, 128)
  const float* b_ih  = (const float*)d_in[3];  // (512,)
  const float* b_hh  = (const float*)d_in[4];  // (512,)
  const float* Wattn = (const float*)d_in[5];  // (1, 320)
  float* out = (float*)d_out;                  // (4096, 64, 128)

  // workspace layout
  float* attn = (float*)d_ws;                                            // 2 MB
  unsigned short* Wc = (unsigned short*)((char*)d_ws + 4096 * 128 * 4);  // 256 KB
  float* biasC = (float*)((char*)d_ws + 4096 * 128 * 4 + 512 * 256 * 2); // 2 KB

  pack_kernel<<<128, 256, 0, stream>>>(W_ih, W_hh, b_ih, b_hh, Wc, biasC);
  attn_kernel<<<4096, 64, 0, stream>>>(x, Wattn, attn);
  lstm_kernel<<<256, 512, 0, stream>>>(x, Wc, biasC, attn, out);
}

// Round 7
// 110.725 us; speedup vs baseline: 5.3734x; 1.0133x over previous
//
#include <hip/hip_runtime.h>

typedef __attribute__((ext_vector_type(4))) float f32x4;
typedef __attribute__((ext_vector_type(8))) short s16x8;

#define MFMA_16x16x32_BF16 __builtin_amdgcn_mfma_f32_16x16x32_bf16

__device__ __forceinline__ unsigned short f2bf(float f) {
  unsigned int u = __builtin_bit_cast(unsigned int, f);
  unsigned int r = (u + 0x7FFFu + ((u >> 16) & 1u)) >> 16;  // RNE
  return (unsigned short)r;
}

__device__ __forceinline__ unsigned int cvt_pk_bf16(float lo, float hi) {
  unsigned int r;
  asm("v_cvt_pk_bf16_f32 %0, %1, %2" : "=v"(r) : "v"(lo), "v"(hi));
  return r;
}

__device__ __forceinline__ float fexp2(float x) {
#if __has_builtin(__builtin_amdgcn_exp2f)
  return __builtin_amdgcn_exp2f(x);
#else
  float r;
  asm("v_exp_f32 %0, %1" : "=v"(r) : "v"(x));
  return r;
#endif
}

// LDS-only barrier: orders ds ops but leaves global loads/stores in flight.
__device__ __forceinline__ void lds_barrier() {
  asm volatile("s_waitcnt lgkmcnt(0)" ::: "memory");
  __builtin_amdgcn_s_barrier();
}

#define RCP __builtin_amdgcn_rcpf
#define L2E 1.442695040888963f   // 1/ln2
#define L2E2 2.885390081777927f  // 2/ln2

// ---- kernel 0: pack Wc = [W_ih | W_hh] (512 x 256) -> bf16 ----
// Weights PRE-SCALED by the exp2 conversion factor of their gate
// (i,f,o: -1/ln2; g: 2/ln2) so the MFMA result is directly exp2-ready.
// biasC likewise pre-scaled (added via MFMA C-init in the lstm kernel).
__global__ __launch_bounds__(256) void pack_kernel(
    const float* __restrict__ Wih, const float* __restrict__ Whh,
    const float* __restrict__ bih, const float* __restrict__ bhh,
    unsigned short* __restrict__ Wc, float* __restrict__ biasC) {
  int i = blockIdx.x * 256 + threadIdx.x;  // 32768 chunks of 4 elems
  int col = i >> 6;
  int k4 = (i & 63) << 2;
  const float s = ((i >> 13) == 2) ? L2E2 : -L2E;  // gate = col>>7 = i>>13
  const float* src = (k4 < 128) ? (Wih + col * 128 + k4)
                                : (Whh + col * 128 + (k4 - 128));
  const float4 v = *reinterpret_cast<const float4*>(src);
  ushort4 u;
  u.x = f2bf(v.x * s); u.y = f2bf(v.y * s);
  u.z = f2bf(v.z * s); u.w = f2bf(v.w * s);
  *reinterpret_cast<ushort4*>(Wc + (size_t)col * 256 + k4) = u;
  if (i < 512) {
    const float b = bih[i] + bhh[i];
    biasC[i] = ((i >> 7) == 2 ? L2E2 : -L2E) * b;
  }
}

// ---- kernel A: attn[b,:] = softmax_d( sum_t x[b,t,:] * wt[t] ) ----
__global__ __launch_bounds__(64) void attn_kernel(
    const float* __restrict__ x, const float* __restrict__ Wattn,
    float* __restrict__ attn) {
  const int b = blockIdx.x;
  const int l = threadIdx.x;  // 0..63
  const float* xb = x + (size_t)b * 64 * 128;
  const float wtl = Wattn[256 + l];
  float s0 = 0.f, s1 = 0.f;
  for (int t = 0; t < 64; ++t) {
    float w = __shfl(wtl, t, 64);
    s0 = fmaf(xb[t * 128 + l], w, s0);
    s1 = fmaf(xb[t * 128 + 64 + l], w, s1);
  }
  float m = fmaxf(s0, s1);
  for (int off = 32; off; off >>= 1) m = fmaxf(m, __shfl_xor(m, off, 64));
  float e0 = __expf(s0 - m), e1 = __expf(s1 - m);
  float sum = e0 + e1;
  for (int off = 32; off; off >>= 1) sum += __shfl_xor(sum, off, 64);
  float inv = RCP(sum);
  attn[(size_t)b * 128 + l] = e0 * inv;
  attn[(size_t)b * 128 + 64 + l] = e1 * inv;
}

// ---- kernel B: persistent LSTM, 2-ahead software pipeline ----
// 512 thr = 8 waves, 16 rows/block, grid 256 (1 block/CU; bfr=128 VGPR/wave).
// Iter i: H-MFMA(i) completes accC (W-part was done in iter i-1, C-init =
// pre-scaled bias); W-MFMA(i+1) into accN overlaps EW(i)'s VALU chain;
// stage w_in(i+2); write h(i); ONE lds_barrier.
// LDS: wbuf0 @0, wbuf1 @4096, hbuf0 @8192, hbuf1 @12288. w_in(k)->wbuf[k&1],
// h(k)->hbuf[k&1]. 16 rows x 128 bf16 each, swizzle byte ^= (row&7)<<4.
__global__ __launch_bounds__(512, 2) void lstm_kernel(
    const float* __restrict__ x, const unsigned short* __restrict__ Wc,
    const float* __restrict__ biasC, const float* __restrict__ attn,
    float* __restrict__ out) {
  __shared__ __attribute__((aligned(16))) char sAb[16384];

  const int tid = threadIdx.x;
  const int l = tid & 63;
  const int w = tid >> 6;   // 0..7
  const int l15 = l & 15;
  const int khi = l >> 4;   // 0..3
  const int rowBase = blockIdx.x * 16;

  // ---- B fragments into registers (once): 4 gates x 8 kt x 16B ----
  s16x8 bfr[4][8];
  float bias2[4];
#pragma unroll
  for (int g = 0; g < 4; ++g) {
    const int col = g * 128 + w * 16 + l15;
    const unsigned short* p = Wc + (size_t)col * 256 + khi * 8;
#pragma unroll
    for (int kt = 0; kt < 8; ++kt)
      bfr[g][kt] = *reinterpret_cast<const s16x8*>(p + kt * 32);
    bias2[g] = biasC[col];
  }

  // ---- staging role: thread -> (row r_st, 4 cols at c_st) ----
  const int r_st = tid >> 5;          // 0..15
  const int c_st = (tid & 31) << 2;   // 0..124
  const float4 at =
      *reinterpret_cast<const float4*>(attn + (size_t)(rowBase + r_st) * 128 + c_st);
  const float* xrow = x + (size_t)(rowBase + r_st) * 8192 + c_st;
  char* stgW = sAb + r_st * 256 + ((c_st << 1) ^ ((r_st & 7) << 4));

  // zero hbuf1 (h(-1) = 0; iter 0 reads hbuf1)
  {
    uint2 z = {0u, 0u};
    *reinterpret_cast<uint2*>(sAb + 12288 + tid * 8) = z;
  }

  // stage w_in(0) -> wbuf0, w_in(1) -> wbuf1
  {
    const float4 x0 = *reinterpret_cast<const float4*>(xrow);
    const float4 x1 = *reinterpret_cast<const float4*>(xrow + 128);
    uint2 u0, u1;
    u0.x = cvt_pk_bf16(x0.x * at.x, x0.y * at.y);
    u0.y = cvt_pk_bf16(x0.z * at.z, x0.w * at.w);
    u1.x = cvt_pk_bf16(x1.x * at.x, x1.y * at.y);
    u1.y = cvt_pk_bf16(x1.z * at.z, x1.w * at.w);
    *reinterpret_cast<uint2*>(stgW) = u0;
    *reinterpret_cast<uint2*>(stgW + 4096) = u1;
  }
  float4 xvE = *reinterpret_cast<const float4*>(xrow + 2 * 128);  // x(2)
  float4 xvO = *reinterpret_cast<const float4*>(xrow + 3 * 128);  // x(3)

  // ---- MFMA read pointers (base = buf0; add RW/RH per parity) ----
  const char* aw[4];
  const char* ah[4];
#pragma unroll
  for (int k = 0; k < 4; ++k) {
    aw[k] = sAb + l15 * 256 + ((k * 64 + khi * 16) ^ ((l15 & 7) << 4));
    ah[k] = aw[k] + 8192;
  }
  // h-write pointers (base = hbuf0)
  char* hw[4];
#pragma unroll
  for (int rr = 0; rr < 4; ++rr) {
    const int row = khi * 4 + rr;
    hw[rr] = sAb + 8192 + row * 256 + (((w * 16 + l15) << 1) ^ ((row & 7) << 4));
  }

  float c4[4] = {0.f, 0.f, 0.f, 0.f};
  float* outP = out + (size_t)(rowBase + khi * 4) * 8192 + w * 16 + l15;

  lds_barrier();

  // pre-loop: accA = bias + W-part(0) (reads wbuf0)
  f32x4 accA[4], accB[4];
#pragma unroll
  for (int g = 0; g < 4; ++g)
    accA[g] = f32x4{bias2[g], bias2[g], bias2[g], bias2[g]};
#pragma unroll
  for (int k = 0; k < 4; ++k) {
    const s16x8 af = *reinterpret_cast<const s16x8*>(aw[k]);
#pragma unroll
    for (int g = 0; g < 4; ++g)
      accA[g] = MFMA_16x16x32_BF16(af, bfr[g][k], accA[g], 0, 0, 0);
  }

#define STEP(T, ACCC, ACCN, RW, RH, SW, WH, XVS)                               \
  {                                                                            \
    __builtin_amdgcn_s_setprio(1);                                             \
    /* H-MFMA(T): complete ACCC with h(T-1) */                                 \
    _Pragma("unroll") for (int k = 0; k < 4; ++k) {                            \
      const s16x8 af = *reinterpret_cast<const s16x8*>(ah[k] + (RH));          \
      _Pragma("unroll") for (int g = 0; g < 4; ++g)                            \
          ACCC[g] = MFMA_16x16x32_BF16(af, bfr[g][4 + k], ACCC[g], 0, 0, 0);   \
    }                                                                          \
    /* W-MFMA(T+1) into ACCN (independent of EW below) */                      \
    _Pragma("unroll") for (int g = 0; g < 4; ++g)                              \
        ACCN[g] = f32x4{bias2[g], bias2[g], bias2[g], bias2[g]};               \
    _Pragma("unroll") for (int k = 0; k < 4; ++k) {                            \
      const s16x8 af = *reinterpret_cast<const s16x8*>(aw[k] + (RW));          \
      _Pragma("unroll") for (int g = 0; g < 4; ++g)                            \
          ACCN[g] = MFMA_16x16x32_BF16(af, bfr[g][k], ACCN[g], 0, 0, 0);       \
    }                                                                          \
    __builtin_amdgcn_s_setprio(0);                                             \
    /* stage w_in(T+2) */                                                      \
    {                                                                          \
      uint2 u;                                                                 \
      u.x = cvt_pk_bf16(XVS.x * at.x, XVS.y * at.y);                           \
      u.y = cvt_pk_bf16(XVS.z * at.z, XVS.w * at.w);                           \
      *reinterpret_cast<uint2*>(stgW + (SW)) = u;                              \
    }                                                                          \
    XVS = *reinterpret_cast<const float4*>(xrow + (((T) + 4) & 63) * 128);     \
    /* EW(T): acc is pre-scaled & biased -> direct exp2 */                     \
    float h4[4];                                                               \
    _Pragma("unroll") for (int rr = 0; rr < 4; ++rr) {                         \
      const float Ei = fexp2(fminf(ACCC[0][rr], 30.f));                        \
      const float Ef = fexp2(fminf(ACCC[1][rr], 30.f));                        \
      const float G  = fexp2(fminf(ACCC[2][rr], 30.f));                        \
      const float Eo = fexp2(fminf(ACCC[3][rr], 30.f));                        \
      const float a1 = 1.f + Ei, a2 = 1.f + Ef, a3 = G + 1.f, a4 = G - 1.f;    \
      const float m1 = a1 * a3;                                                \
      const float cn = fmaf(a2, a4, c4[rr] * m1) * RCP(a2 * m1);               \
      c4[rr] = cn;                                                             \
      const float C2 = fexp2(fminf(cn * L2E2, 30.f));                          \
      const float h = (C2 - 1.f) * RCP((1.f + Eo) * (C2 + 1.f));               \
      h4[rr] = h;                                                              \
      outP[(size_t)rr * 8192 + (T) * 128] = h;                                 \
    }                                                                          \
    /* h(T) -> hbuf[WH] */                                                     \
    {                                                                          \
      const unsigned int r01 = cvt_pk_bf16(h4[0], h4[1]);                      \
      const unsigned int r23 = cvt_pk_bf16(h4[2], h4[3]);                      \
      *reinterpret_cast<unsigned short*>(hw[0] + (WH)) = (unsigned short)r01;  \
      *reinterpret_cast<unsigned short*>(hw[1] + (WH)) =                       \
          (unsigned short)(r01 >> 16);                                         \
      *reinterpret_cast<unsigned short*>(hw[2] + (WH)) = (unsigned short)r23;  \
      *reinterpret_cast<unsigned short*>(hw[3] + (WH)) =                       \
          (unsigned short)(r23 >> 16);                                         \
    }                                                                          \
    lds_barrier();                                                             \
  }

  for (int tt = 0; tt < 32; ++tt) {
    const int t0 = tt * 2;
    // even: read w_in(t+1)@wbuf1, h(t-1)@hbuf1; stage->wbuf0; h->hbuf0
    STEP(t0, accA, accB, 4096, 4096, 0, 0, xvE);
    // odd: read w_in(t+1)@wbuf0, h(t-1)@hbuf0; stage->wbuf1; h->hbuf1
    STEP(t0 + 1, accB, accA, 0, 0, 4096, 4096, xvO);
  }
#undef STEP
}

extern "C" void kernel_launch(void* const* d_in, const int* in_sizes, int n_in,
                              void* d_out, int out_size, void* d_ws, size_t ws_size,
                              hipStream_t stream) {
  const float* x     = (const float*)d_in[0];  // (4096, 64, 128)
  const float* W_ih  = (const float*)d_in[1];  // (512, 128)
  const float* W_hh  = (const float*)d_in[2];  // (512, 128)
  const float* b_ih  = (const float*)d_in[3];  // (512,)
  const float* b_hh  = (const float*)d_in[4];  // (512,)
  const float* Wattn = (const float*)d_in[5];  // (1, 320)
  float* out = (float*)d_out;                  // (4096, 64, 128)

  // workspace layout
  float* attn = (float*)d_ws;                                            // 2 MB
  unsigned short* Wc = (unsigned short*)((char*)d_ws + 4096 * 128 * 4);  // 256 KB
  float* biasC = (float*)((char*)d_ws + 4096 * 128 * 4 + 512 * 256 * 2); // 2 KB

  pack_kernel<<<128, 256, 0, stream>>>(W_ih, W_hh, b_ih, b_hh, Wc, biasC);
  attn_kernel<<<4096, 64, 0, stream>>>(x, Wattn, attn);
  lstm_kernel<<<256, 512, 0, stream>>>(x, Wc, biasC, attn, out);
}